// Round 6
// baseline (429.208 us; speedup 1.0000x reference)
//
#include <hip/hip_runtime.h>
#include <hip/hip_bf16.h>
#include <math.h>

#define NQ 300
#define BSZ 8
#define DIM 256
#define NHEAD 8
#define ROWS 2400  // NQ*BSZ

typedef __attribute__((ext_vector_type(8))) short bf16x8;
typedef __attribute__((ext_vector_type(4))) float f32x4;

__device__ inline short f2bf(float f) {
  __hip_bfloat16 h = __float2bfloat16(f);
  return *reinterpret_cast<short*>(&h);
}
__device__ inline float bf2f(unsigned short u) {
  union { unsigned u; float f; } c;
  c.u = ((unsigned)u) << 16;
  return c.f;
}

// global->LDS 16B direct copy. gsrc includes the lane's 16B offset; ldst is the
// wave-uniform base (HW writes lane i at ldst + i*16).
#if __has_builtin(__builtin_amdgcn_global_load_lds)
__device__ inline void gld16(const void* gsrc, void* ldst, int lane) {
  (void)lane;
  auto g = (const __attribute__((address_space(1))) unsigned int*)gsrc;
  auto l = (__attribute__((address_space(3))) unsigned int*)ldst;
  __builtin_amdgcn_global_load_lds(g, l, 16, 0, 0);
}
#else
__device__ inline void gld16(const void* gsrc, void* ldst, int lane) {
  ((float4*)ldst)[lane] = *(const float4*)gsrc;
}
#endif

__device__ inline bf16x8 cvt8(float4 v0, float4 v1) {
  bf16x8 o;
  o[0] = f2bf(v0.x); o[1] = f2bf(v0.y); o[2] = f2bf(v0.z); o[3] = f2bf(v0.w);
  o[4] = f2bf(v1.x); o[5] = f2bf(v1.y); o[6] = f2bf(v1.z); o[7] = f2bf(v1.w);
  return o;
}

// ---------------- one-shot weight conversion fp32 -> bf16 IMG64 ----------------
// IMG64: per (nb64, c) an 8KB block = 64 rows x 64k bf16; within: byte(rr, g8) =
// rr*128 + ((g8*16) ^ ((rr&7)<<4)). GEMMs stage blocks with a LINEAR gld16 copy and
// read with the same XOR (both-sides rule #21).
struct WEntry { const float* src; unsigned short* dst; int K; int gstart; };
struct WPack { WEntry e[8]; int total; };
__global__ __launch_bounds__(256) void wconv_kernel(WPack P) {
  int g = blockIdx.x * 256 + threadIdx.x;
  if (g >= P.total) return;
  int i = 0;
  while (i < 7 && g >= P.e[i + 1].gstart) ++i;
  const float* src = P.e[i].src;
  unsigned short* dst = P.e[i].dst;
  const int K = P.e[i].K;
  int gl = g - P.e[i].gstart;
  int gpr = K >> 3;
  int r = gl / gpr, gk = gl - r * gpr;
  int nb = r >> 6, rr = r & 63;
  int c = gk >> 3, g8 = gk & 7;
  const float* s = src + (size_t)r * K + gk * 8;
  float4 v0 = *(const float4*)s, v1 = *(const float4*)(s + 4);
  size_t byte = ((size_t)(nb * (K >> 6) + c) * 64 + rr) * 128 + ((g8 * 16) ^ ((rr & 7) << 4));
  *(bf16x8*)((char*)dst + byte) = cvt8(v0, v1);
}

__global__ void bias_cat(const float* __restrict__ a, const float* __restrict__ b,
                         float* __restrict__ o) {
  int t = blockIdx.x * 256 + threadIdx.x;
  if (t < 512) o[t] = a[t];
  else if (t < 768) o[t] = b[t - 512];
}

// ---------------- big GEMM: value = memory(fp32) @ vw^T ----------------
// BM=128, BN=128, K=N=256, BK=64, 2-phase double-buffered pipeline:
// per chunk issue next A (global->reg) + B (gld16) BEFORE the MFMA burst.
// A converted to bf16 at ds_write (IMG row layout, XOR swizzle).
template <bool VMASK>
__global__ __launch_bounds__(256) void vgemm(const float* __restrict__ A,
                                             const unsigned short* __restrict__ Wz,
                                             const float* __restrict__ bias,
                                             __hip_bfloat16* __restrict__ C, int M,
                                             const unsigned char* __restrict__ vmask,
                                             int Srows) {
  __shared__ char As[2][16384];   // 128 rows x 64k bf16, swizzled
  __shared__ char Bsh[2][16384];  // 2 IMG64 blocks per buffer
  const int tid = threadIdx.x, lane = tid & 63, wid = tid >> 6;
  const int wr = wid >> 1, wc = wid & 1;
  const int nb = blockIdx.x;
  const int m0 = blockIdx.y * 128;
  const int l15 = lane & 15, lk = lane >> 4;

  f32x4 acc[4][4];
#pragma unroll
  for (int i = 0; i < 4; ++i)
#pragma unroll
    for (int j = 0; j < 4; ++j) acc[i][j] = {0.f, 0.f, 0.f, 0.f};

  // A staging map: bf-granule gb = j*256+tid (j<4): row=gb>>3, g8=gb&7
  const float* asrc[4];
  int awby[4];
#pragma unroll
  for (int j = 0; j < 4; ++j) {
    int gb = j * 256 + tid;
    int row = gb >> 3, g8 = gb & 7;
    int rg = m0 + row;
    if (rg > M - 1) rg = M - 1;  // dup rows feed discarded outputs only
    asrc[j] = A + (size_t)rg * 256 + g8 * 8;
    awby[j] = row * 128 + ((g8 * 16) ^ ((row & 7) << 4));
  }

  float4 ar[8];
#define V_AISSUE(c)                                        \
  {                                                        \
    _Pragma("unroll") for (int j = 0; j < 4; ++j) {        \
      const float* p = asrc[j] + (c) * 64;                 \
      ar[2 * j] = *(const float4*)p;                       \
      ar[2 * j + 1] = *(const float4*)(p + 4);             \
    }                                                      \
  }
#define V_AWRITE(buf)                                      \
  {                                                        \
    _Pragma("unroll") for (int j = 0; j < 4; ++j)          \
        *(bf16x8*)((buf) + awby[j]) = cvt8(ar[2 * j], ar[2 * j + 1]); \
  }
#define V_BGLD(c, buf)                                                          \
  {                                                                             \
    _Pragma("unroll") for (int i = 0; i < 4; ++i) {                             \
      int bch = wid * 4 + i;                                                    \
      const char* src = (const char*)Wz +                                       \
                        ((size_t)((2 * nb + (bch >> 3)) * 4 + (c))) * 8192 +    \
                        (bch & 7) * 1024 + lane * 16;                           \
      gld16(src, (buf) + bch * 1024, lane);                                     \
    }                                                                           \
  }
#define V_COMPUTE(Ab, Bb)                                                        \
  {                                                                              \
    _Pragma("unroll") for (int kk = 0; kk < 2; ++kk) {                           \
      bf16x8 af[4], bfr[4];                                                      \
      _Pragma("unroll") for (int i = 0; i < 4; ++i) {                            \
        int rr = wr * 64 + i * 16 + l15;                                         \
        af[i] = *(bf16x8*)((Ab) + rr * 128 + (((kk * 4 + lk) * 16) ^ ((rr & 7) << 4))); \
      }                                                                          \
      _Pragma("unroll") for (int j = 0; j < 4; ++j) {                            \
        int rr = wc * 64 + j * 16 + l15;                                         \
        bfr[j] = *(bf16x8*)((Bb) + (rr >> 6) * 8192 + (rr & 63) * 128 +          \
                            (((kk * 4 + lk) * 16) ^ ((rr & 7) << 4)));           \
      }                                                                          \
      _Pragma("unroll") for (int i = 0; i < 4; ++i)                              \
          _Pragma("unroll") for (int j = 0; j < 4; ++j)                          \
              acc[i][j] = __builtin_amdgcn_mfma_f32_16x16x32_bf16(af[i], bfr[j], \
                                                                  acc[i][j], 0, 0, 0); \
    }                                                                            \
  }

  // prologue: stage chunk 0 into buffer 0
  V_AISSUE(0);
  V_BGLD(0, Bsh[0]);
  V_AWRITE(As[0]);
  __syncthreads();
#pragma unroll
  for (int c = 0; c < 4; ++c) {
    const int cur = c & 1;
    if (c < 3) {
      V_AISSUE(c + 1);
      V_BGLD(c + 1, Bsh[cur ^ 1]);
    }
    V_COMPUTE(As[cur], Bsh[cur]);
    if (c < 3) {
      V_AWRITE(As[cur ^ 1]);
      __syncthreads();
    }
  }

#pragma unroll
  for (int i = 0; i < 4; ++i) {
#pragma unroll
    for (int r = 0; r < 4; ++r) {
      int row = m0 + wr * 64 + i * 16 + lk * 4 + r;
      if (row >= M) continue;
      float mfac = 1.f;
      if (VMASK) mfac = vmask[(size_t)(row & 7) * Srows + (row >> 3)] ? 0.f : 1.f;
#pragma unroll
      for (int j = 0; j < 4; ++j) {
        int col = nb * 128 + wc * 64 + j * 16 + l15;
        float v = acc[i][j][r] + bias[col];
        if (VMASK) v *= mfac;
        C[(size_t)row * 256 + col] = __float2bfloat16(v);
      }
    }
  }
}

// ---------------- small GEMM: C = A(fp32)@Wz^T + bias; BN=64, 2-phase dbuf ----------------
// QKV: nb<8 -> out C0 (stride 512, A+Am); nb>=8 -> out C1 (stride 256, plain A).
template <int BM, bool RELU, bool ADDM, bool QKV>
__global__ __launch_bounds__(256) void sgemm(const float* __restrict__ A,
                                             const float* __restrict__ Am,
                                             const unsigned short* __restrict__ Wz,
                                             const float* __restrict__ bias,
                                             float* __restrict__ C0, float* __restrict__ C1,
                                             int M, int Ns, int K) {
  constexpr int WMT = BM / 2, AM = WMT / 16, NA = BM / 32;
  __shared__ char As[2][BM * 128];
  __shared__ char Bsh[2][8192];
  const int tid = threadIdx.x, lane = tid & 63, wid = tid >> 6;
  const int wr = wid >> 1, wc = wid & 1;
  const int nb = blockIdx.x, m0 = blockIdx.y * BM;
  const int l15 = lane & 15, lk = lane >> 4;
  const bool useM = QKV ? (nb < 8) : ADDM;

  f32x4 acc[AM][2];
#pragma unroll
  for (int i = 0; i < AM; ++i)
#pragma unroll
    for (int j = 0; j < 2; ++j) acc[i][j] = {0.f, 0.f, 0.f, 0.f};

  const int nch = K >> 6;
  const float* asrc[NA];
  const float* amsrc[NA];
  int awby[NA];
  bool avalid[NA];
#pragma unroll
  for (int j = 0; j < NA; ++j) {
    int gb = j * 256 + tid;
    int row = gb >> 3, g8 = gb & 7;
    int rg = m0 + row;
    avalid[j] = rg < M;
    if (rg > M - 1) rg = M - 1;
    asrc[j] = A + (size_t)rg * K + g8 * 8;
    amsrc[j] = (useM ? Am : A) + (size_t)rg * K + g8 * 8;
    awby[j] = row * 128 + ((g8 * 16) ^ ((row & 7) << 4));
  }

  float4 ar[2 * NA], am2[2 * NA];
#define S_AISSUE(c)                                          \
  {                                                          \
    _Pragma("unroll") for (int j = 0; j < NA; ++j) {         \
      const float* p = asrc[j] + (c) * 64;                   \
      ar[2 * j] = *(const float4*)p;                         \
      ar[2 * j + 1] = *(const float4*)(p + 4);               \
      if (useM) {                                            \
        const float* q = amsrc[j] + (c) * 64;                \
        am2[2 * j] = *(const float4*)q;                      \
        am2[2 * j + 1] = *(const float4*)(q + 4);            \
      }                                                      \
    }                                                        \
  }
#define S_AWRITE(buf)                                                       \
  {                                                                         \
    _Pragma("unroll") for (int j = 0; j < NA; ++j) {                        \
      float4 v0 = ar[2 * j], v1 = ar[2 * j + 1];                            \
      if (useM) {                                                           \
        float4 w0 = am2[2 * j], w1 = am2[2 * j + 1];                        \
        v0.x += w0.x; v0.y += w0.y; v0.z += w0.z; v0.w += w0.w;             \
        v1.x += w1.x; v1.y += w1.y; v1.z += w1.z; v1.w += w1.w;             \
      }                                                                     \
      if (!avalid[j]) { v0 = make_float4(0.f,0.f,0.f,0.f); v1 = v0; }       \
      *(bf16x8*)((buf) + awby[j]) = cvt8(v0, v1);                           \
    }                                                                       \
  }
#define S_BGLD(c, buf)                                                        \
  {                                                                           \
    _Pragma("unroll") for (int i = 0; i < 2; ++i) {                           \
      int bch = wid * 2 + i;                                                  \
      const char* src = (const char*)Wz + ((size_t)(nb * nch + (c))) * 8192 + \
                        bch * 1024 + lane * 16;                               \
      gld16(src, (buf) + bch * 1024, lane);                                   \
    }                                                                         \
  }
#define S_COMPUTE(Ab, Bb)                                                        \
  {                                                                              \
    _Pragma("unroll") for (int kk = 0; kk < 2; ++kk) {                           \
      bf16x8 af[AM], bfr[2];                                                     \
      _Pragma("unroll") for (int i = 0; i < AM; ++i) {                           \
        int rr = wr * WMT + i * 16 + l15;                                        \
        af[i] = *(bf16x8*)((Ab) + rr * 128 + (((kk * 4 + lk) * 16) ^ ((rr & 7) << 4))); \
      }                                                                          \
      _Pragma("unroll") for (int j = 0; j < 2; ++j) {                            \
        int rr = wc * 32 + j * 16 + l15;                                         \
        bfr[j] = *(bf16x8*)((Bb) + rr * 128 + (((kk * 4 + lk) * 16) ^ ((rr & 7) << 4))); \
      }                                                                          \
      _Pragma("unroll") for (int i = 0; i < AM; ++i)                             \
          _Pragma("unroll") for (int j = 0; j < 2; ++j)                          \
              acc[i][j] = __builtin_amdgcn_mfma_f32_16x16x32_bf16(af[i], bfr[j], \
                                                                  acc[i][j], 0, 0, 0); \
    }                                                                            \
  }

  S_AISSUE(0);
  S_BGLD(0, Bsh[0]);
  S_AWRITE(As[0]);
  __syncthreads();
  for (int c = 0; c < nch; ++c) {
    const int cur = c & 1;
    if (c < nch - 1) {
      S_AISSUE(c + 1);
      S_BGLD(c + 1, Bsh[cur ^ 1]);
    }
    S_COMPUTE(As[cur], Bsh[cur]);
    if (c < nch - 1) {
      S_AWRITE(As[cur ^ 1]);
      __syncthreads();
    }
  }

  float* outp;
  int ostride, ocol0;
  if (QKV) {
    if (nb < 8) { outp = C0; ostride = 512; ocol0 = nb * 64; }
    else        { outp = C1; ostride = 256; ocol0 = (nb - 8) * 64; }
  } else {
    outp = C0; ostride = Ns; ocol0 = nb * 64;
  }
#pragma unroll
  for (int i = 0; i < AM; ++i) {
#pragma unroll
    for (int r = 0; r < 4; ++r) {
      int row = m0 + wr * WMT + i * 16 + lk * 4 + r;
      if (row >= M) continue;
#pragma unroll
      for (int j = 0; j < 2; ++j) {
        int cl = wc * 32 + j * 16 + l15;
        float v = acc[i][j][r] + bias[nb * 64 + cl];
        if (RELU) v = fmaxf(v, 0.f);
        outp[(size_t)row * ostride + ocol0 + cl] = v;
      }
    }
  }
}

// ---------------- self-attention, flash-style (fp32) ----------------
__global__ __launch_bounds__(256) void attn_kernel(const float* __restrict__ cqk,
                                                   const float* __restrict__ cv,
                                                   float* __restrict__ out) {
  __shared__ float Ks[NQ][32];
  __shared__ float Vs[NQ][32];
  const int b = blockIdx.x, h = blockIdx.y, qt = blockIdx.z;
  const int tid = threadIdx.x;
  for (int i = tid; i < NQ * 8; i += 256) {
    int qi = i >> 3, c4 = (i & 7) * 4;
    *(float4*)&Ks[qi][c4] = *(const float4*)&cqk[((size_t)(qi * 8 + b)) * 512 + 256 + h * 32 + c4];
    *(float4*)&Vs[qi][c4] = *(const float4*)&cv[((size_t)(qi * 8 + b)) * 256 + h * 32 + c4];
  }
  __syncthreads();
  const int row = qt * 64 + (tid >> 2);
  const int qr = tid & 3;
  if (row >= NQ) return;
  float qv[8];
  const float* qptr = &cqk[((size_t)(row * 8 + b)) * 512 + h * 32 + qr * 8];
  *(float4*)&qv[0] = *(const float4*)&qptr[0];
  *(float4*)&qv[4] = *(const float4*)&qptr[4];
  const float scale = 0.17677669529663687f;
  float m = -3.0e38f, l = 0.f;
  float acc[8] = {0.f, 0.f, 0.f, 0.f, 0.f, 0.f, 0.f, 0.f};
  for (int k = 0; k < NQ; ++k) {
    const float* kr = &Ks[k][qr * 8];
    float p = 0.f;
#pragma unroll
    for (int j = 0; j < 8; ++j) p = fmaf(qv[j], kr[j], p);
    p += __shfl_xor(p, 1, 4);
    p += __shfl_xor(p, 2, 4);
    float s = p * scale;
    float mn = fmaxf(m, s);
    float corr = __expf(m - mn);
    float e = __expf(s - mn);
    l = l * corr + e;
    const float* vr = &Vs[k][qr * 8];
#pragma unroll
    for (int j = 0; j < 8; ++j) acc[j] = fmaf(acc[j], corr, e * vr[j]);
    m = mn;
  }
  float inv = 1.f / l;
  float* op = &out[((size_t)(row * 8 + b)) * 256 + h * 32 + qr * 8];
#pragma unroll
  for (int j = 0; j < 8; ++j) op[j] = acc[j] * inv;
}

// ---------------- residual + layernorm ----------------
__global__ __launch_bounds__(256) void resid_ln_kernel(const float* __restrict__ X,
                                                       const float* __restrict__ R,
                                                       const float* __restrict__ g,
                                                       const float* __restrict__ be,
                                                       float* __restrict__ out) {
  const int r = blockIdx.x, c = threadIdx.x;
  const size_t i = (size_t)r * 256 + c;
  float x = X[i] + R[i];
  float s = x;
#pragma unroll
  for (int o = 32; o; o >>= 1) s += __shfl_xor(s, o, 64);
  __shared__ float sm[4], sv[4];
  const int w = c >> 6;
  if ((c & 63) == 0) sm[w] = s;
  __syncthreads();
  float mu = (sm[0] + sm[1] + sm[2] + sm[3]) * (1.f / 256.f);
  float d = x - mu;
  float v = d * d;
#pragma unroll
  for (int o = 32; o; o >>= 1) v += __shfl_xor(v, o, 64);
  if ((c & 63) == 0) sv[w] = v;
  __syncthreads();
  float var = (sv[0] + sv[1] + sv[2] + sv[3]) * (1.f / 256.f);
  out[i] = d * (1.f / sqrtf(var + 1e-5f)) * g[c] + be[c];
}

// ---------------- multi-scale deformable sampling (value bf16) ----------------
__global__ __launch_bounds__(256) void deform_kernel(const unsigned short* __restrict__ value,
                                                     const float* __restrict__ offaw,
                                                     const float* __restrict__ bbox,
                                                     const int* __restrict__ spatial,
                                                     const int* __restrict__ lstart,
                                                     float* __restrict__ out, int S) {
  __shared__ int sH[4], sW[4], sL[4];
  __shared__ float sbb[4];
  const int r = blockIdx.x;  // q*8+b
  const int b = r & 7;
  const int tid = threadIdx.x;
  if (tid < 4) {
    sH[tid] = spatial[tid * 2];
    sW[tid] = spatial[tid * 2 + 1];
    sL[tid] = lstart[tid];
    sbb[tid] = bbox[(size_t)r * 4 + tid];
  }
  __syncthreads();
  const float cx = sbb[0], cy = sbb[1], bw = sbb[2], bh = sbb[3];
  float ox = offaw[(size_t)r * 768 + (size_t)tid * 2];
  float oy = offaw[(size_t)r * 768 + (size_t)tid * 2 + 1];
  float a = offaw[(size_t)r * 768 + 512 + tid];
  float mx = a;
#pragma unroll
  for (int o = 16; o; o >>= 1) mx = fmaxf(mx, __shfl_xor(mx, o, 32));
  float e = __expf(a - mx);
  float ssum = e;
#pragma unroll
  for (int o = 16; o; o >>= 1) ssum += __shfl_xor(ssum, o, 32);
  float myaw = e / ssum;

  float acc = 0.f;
  const size_t vb = (size_t)b * 256 + (size_t)tid;
  for (int lp = 0; lp < 32; ++lp) {
    const int l = lp >> 3;
    float bx = __shfl(ox, lp, 32);
    float by = __shfl(oy, lp, 32);
    float alp = __shfl(myaw, lp, 32);
    const float Wf = (float)sW[l], Hf = (float)sH[l];
    const int ls = sL[l], Wi = sW[l];
    float lx = cx + bx * 0.0625f * bw;
    float ly = cy + by * 0.0625f * bh;
    float x = lx * Wf - 0.5f;
    float y = ly * Hf - 0.5f;
    float x0 = floorf(x), y0 = floorf(y);
    float fx = x - x0, fy = y - y0;
    float tap = 0.f;
#pragma unroll
    for (int t = 0; t < 4; ++t) {
      float xi = x0 + (float)(t & 1);
      float yi = y0 + (float)(t >> 1);
      if (xi >= 0.f && yi >= 0.f && xi < Wf && yi < Hf) {
        float wx = (t & 1) ? fx : (1.f - fx);
        float wy = (t >> 1) ? fy : (1.f - fy);
        int idx = ls + (int)yi * Wi + (int)xi;
        tap = fmaf(wx * wy, bf2f(value[(size_t)idx * 2048 + vb]), tap);
      }
    }
    acc = fmaf(alp, tap, acc);
  }
  out[(size_t)r * 256 + tid] = acc;
}

extern "C" void kernel_launch(void* const* d_in, const int* in_sizes, int n_in, void* d_out,
                              int out_size, void* d_ws, size_t ws_size, hipStream_t stream) {
  (void)n_in; (void)out_size; (void)ws_size;
  const float* tgt = (const float*)d_in[0];
  const float* qmask = (const float*)d_in[1];
  const float* bbox = (const float*)d_in[2];
  const float* memory = (const float*)d_in[4];
  const float* ipw = (const float*)d_in[5];
  const float* ipb = (const float*)d_in[6];
  const float* osw = (const float*)d_in[7];
  const float* osb = (const float*)d_in[8];
  const float* n2g = (const float*)d_in[9];
  const float* n2b = (const float*)d_in[10];
  const float* vw = (const float*)d_in[11];
  const float* vbi = (const float*)d_in[12];
  const float* ow = (const float*)d_in[13];
  const float* ob = (const float*)d_in[14];
  const float* aww = (const float*)d_in[15];
  const float* awb = (const float*)d_in[16];
  const float* ocw = (const float*)d_in[17];
  const float* ocb = (const float*)d_in[18];
  const float* n1g = (const float*)d_in[19];
  const float* n1b = (const float*)d_in[20];
  const float* l1w = (const float*)d_in[21];
  const float* l1b = (const float*)d_in[22];
  const float* l2w = (const float*)d_in[23];
  const float* l2b = (const float*)d_in[24];
  const float* n3g = (const float*)d_in[25];
  const float* n3b = (const float*)d_in[26];
  const unsigned char* kpmask = (const unsigned char*)d_in[27];
  const int* spatial = (const int*)d_in[28];
  const int* lstart = (const int*)d_in[29];
  float* out = (float*)d_out;

  const int S = in_sizes[4] / (BSZ * DIM);  // 13294
  const int Mv = S * BSZ;                   // 106352

  float* ws = (float*)d_ws;
  size_t o = 0;
  unsigned short* value = (unsigned short*)(ws + o); o += (size_t)Mv * DIM / 2;  // bf16
  float* cqk = ws + o; o += (size_t)ROWS * 512;
  float* cv = ws + o; o += (size_t)ROWS * DIM;
  float* sraw = ws + o; o += (size_t)ROWS * DIM;
  float* proj = ws + o; o += (size_t)ROWS * DIM;
  float* tgt2 = ws + o; o += (size_t)ROWS * DIM;
  float* tgt3 = ws + o; o += (size_t)ROWS * DIM;
  float* ffn1 = ws + o; o += (size_t)ROWS * 1024;
  float* offaw = ws + o; o += (size_t)ROWS * 768;
  float* obaw = ws + o; o += 768;
  unsigned short* wz = (unsigned short*)(ws + o);
  unsigned short* ipw_z = wz;
  unsigned short* osw_z = ipw_z + 768 * 256;
  unsigned short* vw_z  = osw_z + 256 * 256;
  unsigned short* ow_z  = vw_z + 256 * 256;
  unsigned short* aww_z = ow_z + 512 * 256;   // must follow ow_z (concat N=768)
  unsigned short* ocw_z = aww_z + 256 * 256;
  unsigned short* l1w_z = ocw_z + 256 * 256;
  unsigned short* l2w_z = l1w_z + 1024 * 256;

  // 0. weights -> bf16 IMG64 (one launch) + bias concat
  WPack P;
  int gs = 0;
  auto ent = [&](int idx, const float* s, unsigned short* d, int N_, int K_) {
    P.e[idx] = {s, d, K_, gs};
    gs += N_ * K_ / 8;
  };
  ent(0, ipw, ipw_z, 768, 256);
  ent(1, osw, osw_z, 256, 256);
  ent(2, vw, vw_z, 256, 256);
  ent(3, ow, ow_z, 512, 256);
  ent(4, aww, aww_z, 256, 256);
  ent(5, ocw, ocw_z, 256, 256);
  ent(6, l1w, l1w_z, 1024, 256);
  ent(7, l2w, l2w_z, 256, 1024);
  P.total = gs;
  wconv_kernel<<<dim3((gs + 255) / 256), 256, 0, stream>>>(P);
  bias_cat<<<dim3(3), 256, 0, stream>>>(ob, awb, obaw);

  // 1. fused add + q/k/v projections (dual-A, dual-out)
  sgemm<64, false, false, true><<<dim3(12, 38), 256, 0, stream>>>(
      tgt, qmask, ipw_z, ipb, cqk, cv, ROWS, 0, 256);
  // 2. self-attention
  attn_kernel<<<dim3(BSZ, NHEAD, (NQ + 63) / 64), 256, 0, stream>>>(cqk, cv, sraw);
  // 3. out_sa projection
  sgemm<32, false, false, false><<<dim3(4, 75), 256, 0, stream>>>(
      sraw, nullptr, osw_z, osb, proj, nullptr, ROWS, 256, 256);
  // 4. tgt2 = LN(tgt + sa)
  resid_ln_kernel<<<ROWS, 256, 0, stream>>>(proj, tgt, n2g, n2b, tgt2);
  // 5. value projection (big, masked, bf16 out)
  vgemm<true><<<dim3(2, (Mv + 127) / 128), 256, 0, stream>>>(
      memory, vw_z, vbi, (__hip_bfloat16*)value, Mv, kpmask, S);
  // 6. fused offsets+aw projections (A = tgt2 + qmask), N=768
  sgemm<64, false, true, false><<<dim3(12, 38), 256, 0, stream>>>(
      tgt2, qmask, ow_z, obaw, offaw, nullptr, ROWS, 768, 256);
  // 7. deformable sampling
  deform_kernel<<<ROWS, 256, 0, stream>>>(value, offaw, bbox, spatial, lstart, sraw, S);
  // 8. out_ca projection
  sgemm<32, false, false, false><<<dim3(4, 75), 256, 0, stream>>>(
      sraw, nullptr, ocw_z, ocb, proj, nullptr, ROWS, 256, 256);
  // 9. tgt3 = LN(tgt2 + ca)
  resid_ln_kernel<<<ROWS, 256, 0, stream>>>(proj, tgt2, n1g, n1b, tgt3);
  // 10. FFN lin1 + relu
  sgemm<64, true, false, false><<<dim3(16, 38), 256, 0, stream>>>(
      tgt3, nullptr, l1w_z, l1b, ffn1, nullptr, ROWS, 1024, 256);
  // 11. FFN lin2 (K=1024)
  sgemm<32, false, false, false><<<dim3(4, 75), 256, 0, stream>>>(
      ffn1, nullptr, l2w_z, l2b, proj, nullptr, ROWS, 256, 1024);
  // 12. out = LN(tgt3 + ffn)
  resid_ln_kernel<<<ROWS, 256, 0, stream>>>(proj, tgt3, n3g, n3b, out);
}